// Round 7
// baseline (335.948 us; speedup 1.0000x reference)
//
#include <hip/hip_runtime.h>
#include <hip/hip_bf16.h>

// Head attention, B=8, T=4096, C=512, h=64, prefix-causal mask (j <= max(i,1023)).
// Inputs/output fp32; internal q/Kf/Vf bf16 in ws. Round-13: round-12's
// balanced (qt,kt)-flattened schedule kept (attn dropped below 41us) but the
// separate fold kernel (+6-8us serialized) is deleted: qt fully owned by one
// block (n==1, ~half of segments incl all qt<16) stores normalized output
// directly from LDS; n>=2 qt's use partial store + device-scope threadfence +
// atomicAdd counter, and the LAST arriving block folds the other partials
// (L2-warm, same XCD by b=bx&7) inline, overlapped with other blocks' compute.
// Counters zeroed by wtrans each launch (ws is poisoned). Inner tile body,
// combine tree, proj, wtrans byte-identical to round-12.

typedef short short8 __attribute__((ext_vector_type(8)));   // 8 bf16 = 4 VGPRs
typedef float floatx4 __attribute__((ext_vector_type(4)));

// fp32 -> bf16 RNE (scalar)
static __device__ __forceinline__ unsigned short f2b(float f) {
  unsigned u = __float_as_uint(f);
  unsigned r = (u + 0x7fffu + ((u >> 16) & 1u)) >> 16;
  return (unsigned short)r;
}

// pack 2 fp32 -> bf16x2 dword (RNE packed convert)
static __device__ __forceinline__ unsigned pkbf(float lo, float hi) {
  __hip_bfloat162 t = __float22bfloat162_rn(make_float2(lo, hi));
  unsigned d;
  __builtin_memcpy(&d, &t, 4);
  return d;
}

union S8U {
  short8 s;
  unsigned u[4];
};

// ---------------------------------------------------------------------------
// Kernel 0: weights -> frag-linear Wtf; also zeroes the fold counters.
__global__ __launch_bounds__(256) void wtrans(
    const float* __restrict__ Wq, const float* __restrict__ Wk,
    const float* __restrict__ Wv, unsigned short* __restrict__ Wtf,
    int* __restrict__ cnt) {
  int o = blockIdx.x * 256 + threadIdx.x;  // 0..98303
  if (o < 512) cnt[o] = 0;                 // [8][64] fold counters
  int e = o & 7;
  int ln = (o >> 3) & 63;
  int jg = o >> 9;          // ks*12 + j, 0..191
  int ks = jg / 12;
  int j = jg % 12;
  int m = j >> 2;
  int n = (j & 3) * 16 + (ln & 15);
  int k = ks * 32 + (ln >> 4) * 8 + e;
  const float* W = (m == 0) ? Wq : (m == 1) ? Wk : Wv;
  Wtf[o] = f2b(W[k * 64 + n]);
}

// ---------------------------------------------------------------------------
// Kernel 1: 1024 blocks x 32 rows. Wave pair pr = w>>1 owns rows g0+pr*16..+15;
// parity p = w&1 takes ks = p, p+2, ... (8 iters). No barriers / no LDS in the
// main loop. One LDS combine, then direct register->global epilogue stores.
// q stored pre-scaled by C^-0.5 * log2e (attn's exp2 then needs no multiply).
__global__ __launch_bounds__(256, 3) void proj(
    const float* __restrict__ x, const unsigned short* __restrict__ Wtf,
    unsigned short* __restrict__ q, unsigned short* __restrict__ Kf,
    unsigned short* __restrict__ Vf) {
  __shared__ float Cc[2][12][16][17];  // partial-acc exchange, padded

  const int tid = threadIdx.x;
  const int lane = tid & 63;
  const int w = tid >> 6;
  const int u = lane & 15;
  const int qd = lane >> 4;
  const int pr = w >> 1;   // row-pair: rows g0 + pr*16 .. +15
  const int p = w & 1;     // ks parity
  const int g0 = blockIdx.x * 32;

  floatx4 acc[12];
#pragma unroll
  for (int j = 0; j < 12; ++j) acc[j] = (floatx4)0.0f;

  const float* xr = x + (size_t)(g0 + pr * 16 + u) * 512;

  for (int it = 0; it < 8; ++it) {
    const int ks = p + it * 2;
    floatx4 x0 = *reinterpret_cast<const floatx4*>(&xr[ks * 32 + qd * 8]);
    floatx4 x1 = *reinterpret_cast<const floatx4*>(&xr[ks * 32 + qd * 8 + 4]);
    S8U a;
    a.u[0] = pkbf(x0[0], x0[1]);
    a.u[1] = pkbf(x0[2], x0[3]);
    a.u[2] = pkbf(x1[0], x1[1]);
    a.u[3] = pkbf(x1[2], x1[3]);
#pragma unroll
    for (int j = 0; j < 12; ++j) {
      short8 bfr = *reinterpret_cast<const short8*>(&Wtf[(size_t)(ks * 12 + j) * 512 + lane * 8]);
      acc[j] = __builtin_amdgcn_mfma_f32_16x16x32_bf16(a.s, bfr, acc[j], 0, 0, 0);
    }
  }

  // combine parities: p==1 publishes, p==0 adds
  if (p == 1) {
#pragma unroll
    for (int j = 0; j < 12; ++j)
#pragma unroll
      for (int r = 0; r < 4; ++r)
        Cc[pr][j][qd * 4 + r][u] = acc[j][r];
  }
  __syncthreads();
  if (p == 0) {
#pragma unroll
    for (int j = 0; j < 12; ++j)
#pragma unroll
      for (int r = 0; r < 4; ++r)
        acc[j][r] += Cc[pr][j][qd * 4 + r][u];

    // ---- epilogue (2 active waves, 16 rows each) ----
    const float cexp = 0.04419417382415922f * 1.4426950408889634f;  // C^-0.5*log2e
    const int rbase = g0 + pr * 16;
    const int b = rbase >> 12;
    const int t = rbase & 4095;
    const int kt = t >> 6;
    const int sb = ((blockIdx.x & 1) << 1) + pr;      // K frag row-block in tile
    const int sp = blockIdx.x & 1;                     // V frag s-half in tile
    unsigned short* kfb = Kf + ((size_t)(b * 64 + kt)) * 4096;
    unsigned short* vfb = Vf + ((size_t)(b * 64 + kt)) * 4096;

#pragma unroll
    for (int j = 0; j < 4; ++j)
#pragma unroll
      for (int r = 0; r < 4; ++r) {
        // q row-major, pre-scaled so attn's exp2 needs no multiply
        q[(size_t)(rbase + qd * 4 + r) * 64 + j * 16 + u] = f2b(acc[j][r] * cexp);
        // Kf: frag f = kh*4+sb; lane (qd_f, u_f=qd*4+r), elem e=u&7
        {
          int kh = j >> 1;
          int qd_f = ((j & 1) << 1) + (u >> 3);
          kfb[(size_t)(kh * 4 + sb) * 512 + (qd_f * 16 + (qd * 4 + r)) * 8 + (u & 7)] =
              f2b(acc[4 + j][r]);
        }
        // Vf: frag f = sp*4+mb (mb=j); lane (qd_f, u_f=u), elem e
        {
          int qd_f = pr * 2 + (qd >> 1);
          int e = ((qd & 1) << 2) + r;
          vfb[(size_t)(sp * 4 + j) * 512 + (qd_f * 16 + u) * 8 + e] = f2b(acc[8 + j][r]);
        }
      }
  }
}

// ---------------------------------------------------------------------------
// Kernel 2: flash attention, transposed-S, BALANCED schedule + fused fold.
// 512 blocks (b = bx&7 -> XCD, s = bx>>3 in 0..63). Block s owns flat tiles
// [s*2200/64, (s+1)*2200/64) of the (qt,kt) triangle, split into 1-4
// (qt, kt-range) segments. Per segment: round-0 tile body (4-wave kt-split,
// barrier-free), combine tree, then: n==1 -> direct normalized store;
// n>=2 -> partial store + threadfence + atomic; last arrival folds inline.
__global__ __launch_bounds__(256, 2) void attn(
    const unsigned short* __restrict__ q, const unsigned short* __restrict__ Kf,
    const unsigned short* __restrict__ Vf, float* __restrict__ Op,
    float* __restrict__ Lp, int* __restrict__ cnt, float* __restrict__ out) {
  __shared__ unsigned Pb[4][4][64][4];   // [wave][nb][lane][dword] 16 KB
  __shared__ float OcA[64][68];          // combine buffers [qr][h], padded
  __shared__ float OcB[64][68];
  __shared__ float Lc[4][64];
  __shared__ int lastf;

  const int tid = threadIdx.x;
  const int lane = tid & 63;
  const int w = tid >> 6;
  const int u = lane & 15;
  const int qd = lane >> 4;

  const int bx = blockIdx.x;
  const int b = bx & 7;
  const int s = bx >> 3;                 // schedule slot 0..63

  const int ts = (s * 2200) >> 6;        // first flat tile (inclusive)
  const int te = ((s + 1) * 2200) >> 6;  // last flat tile (exclusive)

  const unsigned short* qp = q + (size_t)b * 4096 * 64;
  const unsigned short* kfp = Kf + (size_t)b * 64 * 4096;
  const unsigned short* vfp = Vf + (size_t)b * 64 * 4096;

  // find first qt covered: largest qt with C(qt) <= ts  (C = cum tiles)
  int qt = 0, cq = 0;
  while (cq + ((qt < 16) ? 16 : (qt + 1)) <= ts) {
    cq += (qt < 16) ? 16 : (qt + 1);
    ++qt;
  }

  int tcur = ts;
  while (tcur < te) {
    const int tq = (qt < 16) ? 16 : (qt + 1);          // tiles in this qt
    const int a = tcur - cq;                           // local kt start
    const int bnd = (tq < te - cq) ? tq : (te - cq);   // local kt end (excl)
    // slot range covering this qt: k0 = first, k1 = last
    int k0 = (cq * 64) / 2200;
    while ((((k0 + 1) * 2200) >> 6) <= cq) ++k0;
    const int lastt = cq + tq - 1;
    int k1 = (lastt * 64) / 2200;
    while ((((k1 + 1) * 2200) >> 6) <= lastt) ++k1;
    const int n = k1 - k0 + 1;                         // partials for this qt
    const int o = s - k0;                              // our ordinal (0..2)
    const int g0 = qt * 64;
    const int diagkt = (qt >= 16) ? qt : -1;

    // Q B-frags (all 64 rows): qB[nb][kh]
    short8 qB[4][2];
#pragma unroll
    for (int nb = 0; nb < 4; ++nb)
#pragma unroll
      for (int kh = 0; kh < 2; ++kh)
        qB[nb][kh] = *reinterpret_cast<const short8*>(
            &qp[(size_t)(g0 + nb * 16 + u) * 64 + kh * 32 + qd * 8]);

    floatx4 OT[4][4];  // [mb][nb]: O^T[h=mb*16+qd*4+r][qr=nb*16+u]
#pragma unroll
    for (int mb = 0; mb < 4; ++mb)
#pragma unroll
      for (int nb = 0; nb < 4; ++nb) OT[mb][nb] = (floatx4)0.0f;
    float L[4] = {0.f, 0.f, 0.f, 0.f};

    for (int kt = a + w; kt < bnd; kt += 4) {
      const unsigned short* kb = kfp + (size_t)kt * 4096;
      const unsigned short* vb = vfp + (size_t)kt * 4096;
      short8 kA[8];  // frag f = kh*4+sb
#pragma unroll
      for (int f = 0; f < 8; ++f)
        kA[f] = *reinterpret_cast<const short8*>(&kb[(size_t)f * 512 + lane * 8]);
      const bool diag = (kt == diagkt);

#pragma unroll
      for (int sp = 0; sp < 2; ++sp) {
        short8 vA[4];  // frag f = sp*4+mb
#pragma unroll
        for (int mb = 0; mb < 4; ++mb)
          vA[mb] = *reinterpret_cast<const short8*>(
              &vb[(size_t)(sp * 4 + mb) * 512 + lane * 8]);

        floatx4 ST[2][4];  // [sbb][nb]: S^T[s=(sp*2+sbb)*16+qd*4+r][qr=nb*16+u]
#pragma unroll
        for (int sbb = 0; sbb < 2; ++sbb)
#pragma unroll
          for (int nb = 0; nb < 4; ++nb) ST[sbb][nb] = (floatx4)0.0f;
#pragma unroll
        for (int kh = 0; kh < 2; ++kh)
#pragma unroll
          for (int sbb = 0; sbb < 2; ++sbb)
#pragma unroll
            for (int nb = 0; nb < 4; ++nb)
              ST[sbb][nb] = __builtin_amdgcn_mfma_f32_16x16x32_bf16(
                  kA[kh * 4 + sp * 2 + sbb], qB[nb][kh], ST[sbb][nb], 0, 0, 0);

        if (diag) {
#pragma unroll
          for (int sbb = 0; sbb < 2; ++sbb)
#pragma unroll
            for (int nb = 0; nb < 4; ++nb)
#pragma unroll
              for (int r = 0; r < 4; ++r) {
                int sl = (sp * 2 + sbb) * 16 + qd * 4 + r;
                int qr = nb * 16 + u;
                if (sl > qr) ST[sbb][nb][r] = -__builtin_inff();
              }
        }

        // exp + L partials + pack to B-frag dwords in LDS (q pre-scaled in proj)
#pragma unroll
        for (int sbb = 0; sbb < 2; ++sbb)
#pragma unroll
          for (int nb = 0; nb < 4; ++nb) {
#pragma unroll
            for (int r = 0; r < 4; ++r)
              ST[sbb][nb][r] = __builtin_amdgcn_exp2f(ST[sbb][nb][r]);
            L[nb] += (ST[sbb][nb][0] + ST[sbb][nb][1]) + (ST[sbb][nb][2] + ST[sbb][nb][3]);
            unsigned lo = pkbf(ST[sbb][nb][0], ST[sbb][nb][1]);
            unsigned hi = pkbf(ST[sbb][nb][2], ST[sbb][nb][3]);
            int dl = (sbb * 2 + (qd >> 1)) * 16 + u;  // dest lane
            int d0 = (qd & 1) * 2;                    // dest dword pair
            *reinterpret_cast<uint2*>(&Pb[w][nb][dl][d0]) = make_uint2(lo, hi);
          }

        // PV: O^T += V^T P^T
#pragma unroll
        for (int nb = 0; nb < 4; ++nb) {
          short8 pB = *reinterpret_cast<const short8*>(&Pb[w][nb][lane][0]);
#pragma unroll
          for (int mb = 0; mb < 4; ++mb)
            OT[mb][nb] = __builtin_amdgcn_mfma_f32_16x16x32_bf16(vA[mb], pB, OT[mb][nb], 0, 0, 0);
        }
      }
    }

    // ---- combine across the 4 kt-split waves (round-0 tree) ----
#pragma unroll
    for (int nb = 0; nb < 4; ++nb) {
      L[nb] += __shfl_xor(L[nb], 16);
      L[nb] += __shfl_xor(L[nb], 32);
    }
    if (lane < 16) {
#pragma unroll
      for (int nb = 0; nb < 4; ++nb) Lc[w][nb * 16 + lane] = L[nb];
    }

    if (w == 1) {
#pragma unroll
      for (int mb = 0; mb < 4; ++mb)
#pragma unroll
        for (int nb = 0; nb < 4; ++nb)
          *reinterpret_cast<floatx4*>(&OcA[nb * 16 + u][mb * 16 + qd * 4]) = OT[mb][nb];
    }
    if (w == 3) {
#pragma unroll
      for (int mb = 0; mb < 4; ++mb)
#pragma unroll
        for (int nb = 0; nb < 4; ++nb)
          *reinterpret_cast<floatx4*>(&OcB[nb * 16 + u][mb * 16 + qd * 4]) = OT[mb][nb];
    }
    __syncthreads();
    if (w == 0) {
#pragma unroll
      for (int mb = 0; mb < 4; ++mb)
#pragma unroll
        for (int nb = 0; nb < 4; ++nb)
          OT[mb][nb] += *reinterpret_cast<const floatx4*>(&OcA[nb * 16 + u][mb * 16 + qd * 4]);
    }
    if (w == 2) {
#pragma unroll
      for (int mb = 0; mb < 4; ++mb)
#pragma unroll
        for (int nb = 0; nb < 4; ++nb) {
          OT[mb][nb] += *reinterpret_cast<const floatx4*>(&OcB[nb * 16 + u][mb * 16 + qd * 4]);
          *reinterpret_cast<floatx4*>(&OcB[nb * 16 + u][mb * 16 + qd * 4]) = OT[mb][nb];
        }
    }
    __syncthreads();
    if (w == 0) {
#pragma unroll
      for (int mb = 0; mb < 4; ++mb)
#pragma unroll
        for (int nb = 0; nb < 4; ++nb) {
          OT[mb][nb] += *reinterpret_cast<const floatx4*>(&OcB[nb * 16 + u][mb * 16 + qd * 4]);
          *reinterpret_cast<floatx4*>(&OcA[nb * 16 + u][mb * 16 + qd * 4]) = OT[mb][nb];
        }
    }
    __syncthreads();

    // ---- output: direct (n==1) or partial + fused fold (n>=2) ----
    {
      const int qr = tid >> 2;
      const int h0 = (tid & 3) * 16;
      const float Lown = (Lc[0][qr] + Lc[1][qr]) + (Lc[2][qr] + Lc[3][qr]);

      if (n == 1) {
        const float inv = 1.0f / Lown;
        float* op = out + ((size_t)(b * 4096 + g0 + qr)) * 64 + h0;
#pragma unroll
        for (int c = 0; c < 4; ++c) {
          floatx4 v = *reinterpret_cast<const floatx4*>(&OcA[qr][h0 + c * 4]);
          v *= inv;
          *reinterpret_cast<floatx4*>(&op[c * 4]) = v;
        }
      } else {
        const size_t pbase = (size_t)((b * 64 + qt) * 3);
        float* op = Op + (pbase + o) * 4096 + qr * 64 + h0;
#pragma unroll
        for (int c = 0; c < 4; ++c)
          *reinterpret_cast<floatx4*>(&op[c * 4]) =
              *reinterpret_cast<const floatx4*>(&OcA[qr][h0 + c * 4]);
        if ((tid & 3) == 0) Lp[(pbase + o) * 64 + qr] = Lown;

        __threadfence();  // publish partials (device scope, XCD-safe)
        if (tid == 0) lastf = (atomicAdd(&cnt[b * 64 + qt], 1) == n - 1);
        __syncthreads();
        if (lastf) {
          __threadfence();  // acquire others' partials
          float Ltot = Lown;
          floatx4 acc[4];
#pragma unroll
          for (int c = 0; c < 4; ++c)
            acc[c] = *reinterpret_cast<const floatx4*>(&OcA[qr][h0 + c * 4]);
          for (int oo = 0; oo < n; ++oo) {
            if (oo == o) continue;
            Ltot += Lp[(pbase + oo) * 64 + qr];
            const float* src = Op + (pbase + oo) * 4096 + qr * 64 + h0;
#pragma unroll
            for (int c = 0; c < 4; ++c)
              acc[c] += *reinterpret_cast<const floatx4*>(&src[c * 4]);
          }
          const float inv = 1.0f / Ltot;
          float* oq = out + ((size_t)(b * 4096 + g0 + qr)) * 64 + h0;
#pragma unroll
          for (int c = 0; c < 4; ++c) {
            floatx4 v = acc[c] * inv;
            *reinterpret_cast<floatx4*>(&oq[c * 4]) = v;
          }
        }
      }
    }
    __syncthreads();  // LDS safe for next segment

    tcur = cq + bnd;
    if (bnd == tq) { cq += tq; ++qt; }
  }
}

// ---------------------------------------------------------------------------
extern "C" void kernel_launch(void* const* d_in, const int* in_sizes, int n_in,
                              void* d_out, int out_size, void* d_ws, size_t ws_size,
                              hipStream_t stream) {
  const float* x  = (const float*)d_in[0];  // [8][4096][512] fp32
  const float* Wq = (const float*)d_in[1];  // [512][64] fp32
  const float* Wk = (const float*)d_in[2];
  const float* Wv = (const float*)d_in[3];

  unsigned short* ws = (unsigned short*)d_ws;
  unsigned short* Wtf = ws;                  // 98304 shorts (frag-linear weights)
  unsigned short* qb = ws + 131072;          // 32768*64 bf16 row-major
  unsigned short* kf = qb + 2097152;         // frag-linear K tiles
  unsigned short* vf = kf + 2097152;         // frag-linear V^T tiles
  // partial buffers (byte offset 16 MiB; prior usage ends at ~12.8 MiB)
  float* Op = (float*)(ws + 8388608);        // [8][64][3][4096] f32 = 25.2 MB
  float* Lp = Op + (size_t)8 * 64 * 3 * 4096; // [8][64][3][64] f32
  int* cnt = (int*)(Lp + (size_t)8 * 64 * 3 * 64);  // [8][64] fold counters

  wtrans<<<384, 256, 0, stream>>>(Wq, Wk, Wv, Wtf, cnt);
  proj<<<1024, 256, 0, stream>>>(x, Wtf, qb, kf, vf);
  attn<<<512, 256, 0, stream>>>(qb, kf, vf, Op, Lp, cnt, (float*)d_out);
}

// Round 8
// 150.421 us; speedup vs baseline: 2.2334x; 2.2334x over previous
//
#include <hip/hip_runtime.h>
#include <hip/hip_bf16.h>

// Head attention, B=8, T=4096, C=512, h=64, prefix-causal mask (j <= max(i,1023)).
// Inputs/output fp32; internal q/Kf/Vf bf16 in ws. Round-14: exact round-0
// structure (best measured 41.8us attn / 146.75 total) + ONE change: K frags
// for the next kt-tile are prefetched via global_load_lds (width 16) into an
// 8KB/wave LDS buffer, read back with ds_read_b128 at iter end. Zero extra
// VGPRs (reg-prefetch spilled in R7/R8); LDS unchanged at 52224B because the
// staging buffers overlay the post-loop combine buffers (union) -- one added
// __syncthreads() after the main loop protects the overlay. R13's atomics/
// fences and R12's balanced schedule are reverted (fences serialized; balance
// capped). cexp fold into q kept. proj/wtrans as round-0.

typedef short short8 __attribute__((ext_vector_type(8)));   // 8 bf16 = 4 VGPRs
typedef float floatx4 __attribute__((ext_vector_type(4)));

// fp32 -> bf16 RNE (scalar)
static __device__ __forceinline__ unsigned short f2b(float f) {
  unsigned u = __float_as_uint(f);
  unsigned r = (u + 0x7fffu + ((u >> 16) & 1u)) >> 16;
  return (unsigned short)r;
}

// pack 2 fp32 -> bf16x2 dword (RNE packed convert)
static __device__ __forceinline__ unsigned pkbf(float lo, float hi) {
  __hip_bfloat162 t = __float22bfloat162_rn(make_float2(lo, hi));
  unsigned d;
  __builtin_memcpy(&d, &t, 4);
  return d;
}

union S8U {
  short8 s;
  unsigned u[4];
};

// async global->LDS, 16B per lane. gptr is PER-LANE, lptr is wave-uniform
// base (HW adds lane*16).
static __device__ __forceinline__ void gload_lds16(const void* g, void* l) {
  __builtin_amdgcn_global_load_lds(
      (const __attribute__((address_space(1))) unsigned int*)g,
      (__attribute__((address_space(3))) unsigned int*)l, 16, 0, 0);
}

// ---------------------------------------------------------------------------
// Kernel 0: weights -> frag-linear Wtf[(ks*12 + j)*512 + lane*8 + e] bf16.
__global__ __launch_bounds__(256) void wtrans(
    const float* __restrict__ Wq, const float* __restrict__ Wk,
    const float* __restrict__ Wv, unsigned short* __restrict__ Wtf) {
  int o = blockIdx.x * 256 + threadIdx.x;  // 0..98303
  int e = o & 7;
  int ln = (o >> 3) & 63;
  int jg = o >> 9;          // ks*12 + j, 0..191
  int ks = jg / 12;
  int j = jg % 12;
  int m = j >> 2;
  int n = (j & 3) * 16 + (ln & 15);
  int k = ks * 32 + (ln >> 4) * 8 + e;
  const float* W = (m == 0) ? Wq : (m == 1) ? Wk : Wv;
  Wtf[o] = f2b(W[k * 64 + n]);
}

// ---------------------------------------------------------------------------
// Kernel 1: 1024 blocks x 32 rows. Wave pair pr = w>>1 owns rows g0+pr*16..+15;
// parity p = w&1 takes ks = p, p+2, ... (8 iters). No barriers / no LDS in the
// main loop. One LDS combine, then direct register->global epilogue stores.
// q stored pre-scaled by C^-0.5 * log2e (attn's exp2 then needs no multiply).
__global__ __launch_bounds__(256, 3) void proj(
    const float* __restrict__ x, const unsigned short* __restrict__ Wtf,
    unsigned short* __restrict__ q, unsigned short* __restrict__ Kf,
    unsigned short* __restrict__ Vf) {
  __shared__ float Cc[2][12][16][17];  // partial-acc exchange, padded

  const int tid = threadIdx.x;
  const int lane = tid & 63;
  const int w = tid >> 6;
  const int u = lane & 15;
  const int qd = lane >> 4;
  const int pr = w >> 1;   // row-pair: rows g0 + pr*16 .. +15
  const int p = w & 1;     // ks parity
  const int g0 = blockIdx.x * 32;

  floatx4 acc[12];
#pragma unroll
  for (int j = 0; j < 12; ++j) acc[j] = (floatx4)0.0f;

  const float* xr = x + (size_t)(g0 + pr * 16 + u) * 512;

  for (int it = 0; it < 8; ++it) {
    const int ks = p + it * 2;
    floatx4 x0 = *reinterpret_cast<const floatx4*>(&xr[ks * 32 + qd * 8]);
    floatx4 x1 = *reinterpret_cast<const floatx4*>(&xr[ks * 32 + qd * 8 + 4]);
    S8U a;
    a.u[0] = pkbf(x0[0], x0[1]);
    a.u[1] = pkbf(x0[2], x0[3]);
    a.u[2] = pkbf(x1[0], x1[1]);
    a.u[3] = pkbf(x1[2], x1[3]);
#pragma unroll
    for (int j = 0; j < 12; ++j) {
      short8 bfr = *reinterpret_cast<const short8*>(&Wtf[(size_t)(ks * 12 + j) * 512 + lane * 8]);
      acc[j] = __builtin_amdgcn_mfma_f32_16x16x32_bf16(a.s, bfr, acc[j], 0, 0, 0);
    }
  }

  // combine parities: p==1 publishes, p==0 adds
  if (p == 1) {
#pragma unroll
    for (int j = 0; j < 12; ++j)
#pragma unroll
      for (int r = 0; r < 4; ++r)
        Cc[pr][j][qd * 4 + r][u] = acc[j][r];
  }
  __syncthreads();
  if (p == 0) {
#pragma unroll
    for (int j = 0; j < 12; ++j)
#pragma unroll
      for (int r = 0; r < 4; ++r)
        acc[j][r] += Cc[pr][j][qd * 4 + r][u];

    // ---- epilogue (2 active waves, 16 rows each) ----
    const float cexp = 0.04419417382415922f * 1.4426950408889634f;  // C^-0.5*log2e
    const int rbase = g0 + pr * 16;
    const int b = rbase >> 12;
    const int t = rbase & 4095;
    const int kt = t >> 6;
    const int sb = ((blockIdx.x & 1) << 1) + pr;      // K frag row-block in tile
    const int sp = blockIdx.x & 1;                     // V frag s-half in tile
    unsigned short* kfb = Kf + ((size_t)(b * 64 + kt)) * 4096;
    unsigned short* vfb = Vf + ((size_t)(b * 64 + kt)) * 4096;

#pragma unroll
    for (int j = 0; j < 4; ++j)
#pragma unroll
      for (int r = 0; r < 4; ++r) {
        // q row-major, pre-scaled so attn's exp2 needs no multiply
        q[(size_t)(rbase + qd * 4 + r) * 64 + j * 16 + u] = f2b(acc[j][r] * cexp);
        // Kf: frag f = kh*4+sb; lane (qd_f, u_f=qd*4+r), elem e=u&7
        {
          int kh = j >> 1;
          int qd_f = ((j & 1) << 1) + (u >> 3);
          kfb[(size_t)(kh * 4 + sb) * 512 + (qd_f * 16 + (qd * 4 + r)) * 8 + (u & 7)] =
              f2b(acc[4 + j][r]);
        }
        // Vf: frag f = sp*4+mb (mb=j); lane (qd_f, u_f=u), elem e
        {
          int qd_f = pr * 2 + (qd >> 1);
          int e = ((qd & 1) << 2) + r;
          vfb[(size_t)(sp * 4 + j) * 512 + (qd_f * 16 + u) * 8 + e] = f2b(acc[8 + j][r]);
        }
      }
  }
}

// ---------------------------------------------------------------------------
// Kernel 2: flash attention, transposed-S. 512 blocks (b = bx&7 -> XCD, qt
// paired heavy/light). 4 waves each own ALL 64 q-rows for kt = w, w+4, ...
// S^T = K Q^T; P^T packed in-register to B-frags via LDS bounce; O^T = V^T P^T.
// NEW: next tile's K frags stream global->LDS via global_load_lds (8 x 16B,
// zero VGPR cost) issued at iter start; read back to kA at iter end after
// vmcnt(0). Staging overlays the combine buffers (union, LDS = 52224B as R0).
__global__ __launch_bounds__(256, 2) void attn(
    const unsigned short* __restrict__ q, const unsigned short* __restrict__ Kf,
    const unsigned short* __restrict__ Vf, float* __restrict__ out) {
  union SU {
    unsigned short Kp[4][4096];      // per-wave 8KB K staging (in-loop) 32 KB
    struct {
      float OcA[64][68];             // combine buffers (post-loop) 34.8 KB
      float OcB[64][68];
    } oc;
  };
  __shared__ SU sh;
  __shared__ unsigned Pb[4][4][64][4];   // [wave][nb][lane][dword] 16 KB
  __shared__ float Lc[4][64];

  const int tid = threadIdx.x;
  const int lane = tid & 63;
  const int w = tid >> 6;
  const int u = lane & 15;
  const int qd = lane >> 4;

  const int bx = blockIdx.x;
  const int b = bx & 7;
  const int i = bx >> 3;
  const int qt = (i < 32) ? i : (95 - i);
  const int g0 = qt * 64;

  const unsigned short* qp = q + (size_t)b * 4096 * 64;
  const unsigned short* kfp = Kf + (size_t)b * 64 * 4096;
  const unsigned short* vfp = Vf + (size_t)b * 64 * 4096;

  // Q B-frags (all 64 rows): qB[nb][kh]
  short8 qB[4][2];
#pragma unroll
  for (int nb = 0; nb < 4; ++nb)
#pragma unroll
    for (int kh = 0; kh < 2; ++kh)
      qB[nb][kh] = *reinterpret_cast<const short8*>(
          &qp[(size_t)(g0 + nb * 16 + u) * 64 + kh * 32 + qd * 8]);

  floatx4 OT[4][4];  // [mb][nb]: O^T[h=mb*16+qd*4+r][qr=nb*16+u]
#pragma unroll
  for (int mb = 0; mb < 4; ++mb)
#pragma unroll
    for (int nb = 0; nb < 4; ++nb) OT[mb][nb] = (floatx4)0.0f;
  float L[4] = {0.f, 0.f, 0.f, 0.f};

  const int ktmax = (qt < 16) ? 15 : qt;

  // K staging: DMA tile's 8 frags (frag f = 1KB, lane-linear 16B) into Kp[w]
#define KDMA(SRC)                                                          \
  do {                                                                     \
    _Pragma("unroll")                                                      \
    for (int f = 0; f < 8; ++f)                                            \
      gload_lds16((SRC) + (size_t)f * 512 + lane * 8, &sh.Kp[w][f * 512]); \
  } while (0)

  short8 kA[8];  // current tile's K frags (registers)
  // prologue: stage tile kt=w, wait, read to regs
  KDMA(kfp + (size_t)w * 4096);
  asm volatile("s_waitcnt vmcnt(0)" ::: "memory");
#pragma unroll
  for (int f = 0; f < 8; ++f)
    kA[f] = *reinterpret_cast<const short8*>(&sh.Kp[w][f * 512 + lane * 8]);

  for (int kt = w; kt <= ktmax; kt += 4) {
    const bool havenext = (kt + 4 <= ktmax);
    if (havenext) {
      // kA regs hold current K (ds_read drained by compiler's lgkmcnt before
      // first use); safe to overwrite the staging buffer now.
      asm volatile("s_waitcnt lgkmcnt(0)" ::: "memory");
      KDMA(kfp + (size_t)(kt + 4) * 4096);
    }

    const unsigned short* vb = vfp + (size_t)kt * 4096;
    const bool diag = (qt >= 16) && (kt == qt);

#pragma unroll
    for (int sp = 0; sp < 2; ++sp) {
      short8 vA[4];  // frag f = sp*4+mb
#pragma unroll
      for (int mb = 0; mb < 4; ++mb)
        vA[mb] = *reinterpret_cast<const short8*>(
            &vb[(size_t)(sp * 4 + mb) * 512 + lane * 8]);

      floatx4 ST[2][4];  // [sbb][nb]: S^T[s=(sp*2+sbb)*16+qd*4+r][qr=nb*16+u]
#pragma unroll
      for (int sbb = 0; sbb < 2; ++sbb)
#pragma unroll
        for (int nb = 0; nb < 4; ++nb) ST[sbb][nb] = (floatx4)0.0f;
#pragma unroll
      for (int kh = 0; kh < 2; ++kh)
#pragma unroll
        for (int sbb = 0; sbb < 2; ++sbb)
#pragma unroll
          for (int nb = 0; nb < 4; ++nb)
            ST[sbb][nb] = __builtin_amdgcn_mfma_f32_16x16x32_bf16(
                kA[kh * 4 + sp * 2 + sbb], qB[nb][kh], ST[sbb][nb], 0, 0, 0);

      if (diag) {
#pragma unroll
        for (int sbb = 0; sbb < 2; ++sbb)
#pragma unroll
          for (int nb = 0; nb < 4; ++nb)
#pragma unroll
            for (int r = 0; r < 4; ++r) {
              int sl = (sp * 2 + sbb) * 16 + qd * 4 + r;
              int qr = nb * 16 + u;
              if (sl > qr) ST[sbb][nb][r] = -__builtin_inff();
            }
      }

      // exp + L partials + pack to B-frag dwords in LDS (q pre-scaled in proj)
#pragma unroll
      for (int sbb = 0; sbb < 2; ++sbb)
#pragma unroll
        for (int nb = 0; nb < 4; ++nb) {
#pragma unroll
          for (int r = 0; r < 4; ++r)
            ST[sbb][nb][r] = __builtin_amdgcn_exp2f(ST[sbb][nb][r]);
          L[nb] += (ST[sbb][nb][0] + ST[sbb][nb][1]) + (ST[sbb][nb][2] + ST[sbb][nb][3]);
          unsigned lo = pkbf(ST[sbb][nb][0], ST[sbb][nb][1]);
          unsigned hi = pkbf(ST[sbb][nb][2], ST[sbb][nb][3]);
          int dl = (sbb * 2 + (qd >> 1)) * 16 + u;  // dest lane
          int d0 = (qd & 1) * 2;                    // dest dword pair
          *reinterpret_cast<uint2*>(&Pb[w][nb][dl][d0]) = make_uint2(lo, hi);
        }

      // PV: O^T += V^T P^T
#pragma unroll
      for (int nb = 0; nb < 4; ++nb) {
        short8 pB = *reinterpret_cast<const short8*>(&Pb[w][nb][lane][0]);
#pragma unroll
        for (int mb = 0; mb < 4; ++mb)
          OT[mb][nb] = __builtin_amdgcn_mfma_f32_16x16x32_bf16(vA[mb], pB, OT[mb][nb], 0, 0, 0);
      }
    }

    if (havenext) {
      // next K has been streaming during the whole tile body; land it
      asm volatile("s_waitcnt vmcnt(0)" ::: "memory");
#pragma unroll
      for (int f = 0; f < 8; ++f)
        kA[f] = *reinterpret_cast<const short8*>(&sh.Kp[w][f * 512 + lane * 8]);
    }
  }
#undef KDMA

  __syncthreads();  // staging dead; overlay (Oc*) safe from here on

  // ---- combine across the 4 kt-split waves ----
#pragma unroll
  for (int nb = 0; nb < 4; ++nb) {
    L[nb] += __shfl_xor(L[nb], 16);
    L[nb] += __shfl_xor(L[nb], 32);
  }
  if (lane < 16) {
#pragma unroll
    for (int nb = 0; nb < 4; ++nb) Lc[w][nb * 16 + lane] = L[nb];
  }

  if (w == 1) {
#pragma unroll
    for (int mb = 0; mb < 4; ++mb)
#pragma unroll
      for (int nb = 0; nb < 4; ++nb)
        *reinterpret_cast<floatx4*>(&sh.oc.OcA[nb * 16 + u][mb * 16 + qd * 4]) = OT[mb][nb];
  }
  if (w == 3) {
#pragma unroll
    for (int mb = 0; mb < 4; ++mb)
#pragma unroll
      for (int nb = 0; nb < 4; ++nb)
        *reinterpret_cast<floatx4*>(&sh.oc.OcB[nb * 16 + u][mb * 16 + qd * 4]) = OT[mb][nb];
  }
  __syncthreads();
  if (w == 0) {
#pragma unroll
    for (int mb = 0; mb < 4; ++mb)
#pragma unroll
      for (int nb = 0; nb < 4; ++nb)
        OT[mb][nb] += *reinterpret_cast<const floatx4*>(&sh.oc.OcA[nb * 16 + u][mb * 16 + qd * 4]);
  }
  if (w == 2) {
#pragma unroll
    for (int mb = 0; mb < 4; ++mb)
#pragma unroll
      for (int nb = 0; nb < 4; ++nb) {
        OT[mb][nb] += *reinterpret_cast<const floatx4*>(&sh.oc.OcB[nb * 16 + u][mb * 16 + qd * 4]);
        *reinterpret_cast<floatx4*>(&sh.oc.OcB[nb * 16 + u][mb * 16 + qd * 4]) = OT[mb][nb];
      }
  }
  __syncthreads();
  if (w == 0) {
#pragma unroll
    for (int mb = 0; mb < 4; ++mb)
#pragma unroll
      for (int nb = 0; nb < 4; ++nb) {
        OT[mb][nb] += *reinterpret_cast<const floatx4*>(&sh.oc.OcB[nb * 16 + u][mb * 16 + qd * 4]);
        *reinterpret_cast<floatx4*>(&sh.oc.OcA[nb * 16 + u][mb * 16 + qd * 4]) = OT[mb][nb];
      }
  }
  __syncthreads();

  // cooperative normalize + coalesced store
  {
    int qr = tid >> 2;
    int h0 = (tid & 3) * 16;
    float Ltot = (Lc[0][qr] + Lc[1][qr]) + (Lc[2][qr] + Lc[3][qr]);
    float inv = 1.0f / Ltot;
    float* op = out + ((size_t)b * 4096 + g0 + qr) * 64 + h0;
#pragma unroll
    for (int c = 0; c < 4; ++c) {
      floatx4 v = *reinterpret_cast<const floatx4*>(&sh.oc.OcA[qr][h0 + c * 4]);
      v *= inv;
      *reinterpret_cast<floatx4*>(&op[c * 4]) = v;
    }
  }
}

// ---------------------------------------------------------------------------
extern "C" void kernel_launch(void* const* d_in, const int* in_sizes, int n_in,
                              void* d_out, int out_size, void* d_ws, size_t ws_size,
                              hipStream_t stream) {
  const float* x  = (const float*)d_in[0];  // [8][4096][512] fp32
  const float* Wq = (const float*)d_in[1];  // [512][64] fp32
  const float* Wk = (const float*)d_in[2];
  const float* Wv = (const float*)d_in[3];

  unsigned short* ws = (unsigned short*)d_ws;
  unsigned short* Wtf = ws;                  // 98304 shorts (frag-linear weights)
  unsigned short* qb = ws + 131072;          // 32768*64 bf16 row-major
  unsigned short* kf = qb + 2097152;         // frag-linear K tiles
  unsigned short* vf = kf + 2097152;         // frag-linear V^T tiles

  wtrans<<<384, 256, 0, stream>>>(Wq, Wk, Wv, Wtf);
  proj<<<1024, 256, 0, stream>>>(x, Wtf, qb, kf, vf);
  attn<<<512, 256, 0, stream>>>(qb, kf, vf, (float*)d_out);
}